// Round 2
// baseline (182.491 us; speedup 1.0000x reference)
//
#include <hip/hip_runtime.h>

typedef float f4 __attribute__((ext_vector_type(4)));

__device__ __forceinline__ unsigned int part1by2(unsigned int n) {
    n &= 1023u;
    n = (n ^ (n << 16)) & 0xFF0000FFu;  // 4278190335
    n = (n ^ (n << 8))  & 0x0300F00Fu;  // 50393103
    n = (n ^ (n << 4))  & 0x030C30C3u;  // 51130563
    n = (n ^ (n << 2))  & 0x09249249u;  // 153391689
    return n;
}

#define U 8   // quads per thread; block covers 256*U = 2048 consecutive quads

// Quad id q = 16B chunk of the output. r = q>>3 = output row, i = r>>3 = parent,
// j = r&7 = child, kq = q&7 = quad-within-row. Within a thread, kq and j are
// invariant across the U iterations (256 % 64 == 0), only the parent advances
// by 4 per iteration — so the role branch hoists out of the loop.
__global__ __launch_bounds__(256) void asv_kernel(
    const float* __restrict__ positions,
    const float* __restrict__ sizes,
    const float* __restrict__ densities,
    const float* __restrict__ colors,
    const int*   __restrict__ level_p,
    float* __restrict__ out,
    float* __restrict__ morton_out,
    int N)
{
    const int tid   = threadIdx.x;
    const int qbase = blockIdx.x * (256 * U) + tid;   // quad for u=0
    const int kq    = tid & 7;
    const int i0    = qbase >> 6;                     // parent for u=0
    f4* __restrict__ outv = (f4*)out;

    if (kq == 0) {
        const int   gr  = 64 << level_p[0];
        const float grf = (float)gr;
        const int   j   = (tid >> 3) & 7;             // invariant child index
        const float sx  = (j & 1) ? 0.25f : -0.25f;
        const float sy  = (j & 2) ? 0.25f : -0.25f;
        const float sz  = (j & 4) ? 0.25f : -0.25f;
        #pragma unroll
        for (int u = 0; u < U; ++u) {
            const int i = i0 + 4 * u;
            if (i >= N) break;
            const int q = qbase + u * 256;
            const int r = q >> 3;

            float s  = sizes[i];
            float px = positions[3 * i + 0];
            float py = positions[3 * i + 1];
            float pz = positions[3 * i + 2];
            // match jnp rounding: t = off*size exact, then one rounded add
            float cx = __fadd_rn(px, sx * s);
            float cy = __fadd_rn(py, sy * s);
            float cz = __fadd_rn(pz, sz * s);

            int ix = (int)(__fmul_rn(__fmul_rn(__fadd_rn(cx, 1.0f), 0.5f), grf));
            int iy = (int)(__fmul_rn(__fmul_rn(__fadd_rn(cy, 1.0f), 0.5f), grf));
            int iz = (int)(__fmul_rn(__fmul_rn(__fadd_rn(cz, 1.0f), 0.5f), grf));
            ix = min(max(ix, 0), gr - 1);
            iy = min(max(iy, 0), gr - 1);
            iz = min(max(iz, 0), gr - 1);

            unsigned int code = (part1by2((unsigned)iz) << 2)
                              | (part1by2((unsigned)iy) << 1)
                              |  part1by2((unsigned)ix);
            morton_out[r] = (float)(int)code;

            f4 v = {cx, cy, cz, 0.5f * s};
            outv[q] = v;
        }
    } else if (kq == 1) {
        #pragma unroll
        for (int u = 0; u < U; ++u) {
            const int i = i0 + 4 * u;
            if (i >= N) break;
            const int q = qbase + u * 256;
            const float* c = colors + (size_t)i * 27;
            f4 v = {densities[i], c[0], c[1], c[2]};
            outv[q] = v;
        }
    } else {
        const int off = 4 * kq - 5;
        #pragma unroll
        for (int u = 0; u < U; ++u) {
            const int i = i0 + 4 * u;
            if (i >= N) break;
            const int q = qbase + u * 256;
            const float* c = colors + (size_t)i * 27 + off;
            f4 v = {c[0], c[1], c[2], c[3]};
            outv[q] = v;
        }
    }
}

extern "C" void kernel_launch(void* const* d_in, const int* in_sizes, int n_in,
                              void* d_out, int out_size, void* d_ws, size_t ws_size,
                              hipStream_t stream) {
    const float* positions = (const float*)d_in[0];
    const float* sizes     = (const float*)d_in[1];
    const float* densities = (const float*)d_in[2];
    const float* colors    = (const float*)d_in[3];
    const int*   level_p   = (const int*)d_in[4];

    int N = in_sizes[1];                      // sizes has N elements
    float* out        = (float*)d_out;
    float* morton_out = out + (size_t)N * 8 * 32;

    long long T = (long long)N * 64;          // total quads
    int blocks  = (int)((T + 256 * U - 1) / (256 * U));
    asv_kernel<<<blocks, 256, 0, stream>>>(positions, sizes, densities, colors,
                                           level_p, out, morton_out, N);
}

// Round 3
// 67.403 us; speedup vs baseline: 2.7075x; 2.7075x over previous
//
#include <hip/hip_runtime.h>

typedef float f4 __attribute__((ext_vector_type(4)));

#define P   32   // parents per block
#define REC 36   // dwords per LDS record: 16B-aligned stride, banks spread by 4p

__device__ __forceinline__ unsigned int part1by2(unsigned int n) {
    n &= 1023u;
    n = (n ^ (n << 16)) & 0xFF0000FFu;
    n = (n ^ (n << 8))  & 0x0300F00Fu;
    n = (n ^ (n << 4))  & 0x030C30C3u;
    n = (n ^ (n << 2))  & 0x09249249u;
    return n;
}

// Block = 256 threads handles P=32 parents = 2048 output quads (8/thread).
// Phase 1: coalesced global->LDS staging of parent records [pos3,s,dens,col27].
// Phase 2: quad q -> row r=q>>3, parent p=r>>3, kq=q&7. Record word w == output
// col w for w>=4, so kq>=1 lanes store their LDS 16B verbatim; kq==0 lanes read
// {px,py,pz,s} and compute child pos + size/2 + morton.
__global__ __launch_bounds__(256) void asv_kernel(
    const float* __restrict__ positions,
    const float* __restrict__ sizes,
    const float* __restrict__ densities,
    const float* __restrict__ colors,
    const int*   __restrict__ level_p,
    float* __restrict__ out,
    float* __restrict__ morton_out,
    int N)
{
    __shared__ float rec[P * REC];
    const int tid  = threadIdx.x;
    const int base = blockIdx.x * P;
    const int nloc = min(P, N - base);

    // ---- phase 1: staging (different waves handle different arrays) ----
    if (tid < nloc)
        rec[tid * REC + 3] = sizes[base + tid];
    if (tid >= 64 && tid < 64 + nloc)
        rec[(tid - 64) * REC + 4] = densities[base + (tid - 64)];
    if (tid >= 128 && tid < 128 + nloc * 3) {
        int k = tid - 128;
        rec[(k / 3) * REC + (k % 3)] = positions[(size_t)base * 3 + k];
    }
    for (int k = tid; k < nloc * 27; k += 256)
        rec[(k / 27) * REC + 5 + (k % 27)] = colors[(size_t)base * 27 + k];
    __syncthreads();

    // ---- phase 2: 8 independent LDS-read -> store iterations per thread ----
    const int kq = tid & 7;
    const int j  = (tid >> 3) & 7;                 // child index, loop-invariant
    const float sx = (j & 1) ? 0.25f : -0.25f;
    const float sy = (j & 2) ? 0.25f : -0.25f;
    const float sz = (j & 4) ? 0.25f : -0.25f;
    const int   gr  = 64 << level_p[0];
    const float grf = (float)gr;

    f4* __restrict__ outv = (f4*)out;
    const int qblock = blockIdx.x * (P * 64);      // first quad of this block

    #pragma unroll
    for (int u = 0; u < 8; ++u) {
        const int lq = u * 256 + tid;              // local quad 0..2047
        const int p  = lq >> 6;                    // local parent
        if (p < nloc) {
            f4 v = *(const f4*)&rec[p * REC + kq * 4];
            if (kq == 0) {
                const float px = v.x, py = v.y, pz = v.z, s = v.w;
                // match jnp rounding: off*size exact, then one rounded add
                const float cx = __fadd_rn(px, sx * s);
                const float cy = __fadd_rn(py, sy * s);
                const float cz = __fadd_rn(pz, sz * s);

                int ix = (int)(__fmul_rn(__fmul_rn(__fadd_rn(cx, 1.0f), 0.5f), grf));
                int iy = (int)(__fmul_rn(__fmul_rn(__fadd_rn(cy, 1.0f), 0.5f), grf));
                int iz = (int)(__fmul_rn(__fmul_rn(__fadd_rn(cz, 1.0f), 0.5f), grf));
                ix = min(max(ix, 0), gr - 1);
                iy = min(max(iy, 0), gr - 1);
                iz = min(max(iz, 0), gr - 1);

                unsigned int code = (part1by2((unsigned)iz) << 2)
                                  | (part1by2((unsigned)iy) << 1)
                                  |  part1by2((unsigned)ix);
                morton_out[(qblock + lq) >> 3] = (float)(int)code;

                f4 w = {cx, cy, cz, 0.5f * s};
                v = w;
            }
            outv[qblock + lq] = v;
        }
    }
}

extern "C" void kernel_launch(void* const* d_in, const int* in_sizes, int n_in,
                              void* d_out, int out_size, void* d_ws, size_t ws_size,
                              hipStream_t stream) {
    const float* positions = (const float*)d_in[0];
    const float* sizes     = (const float*)d_in[1];
    const float* densities = (const float*)d_in[2];
    const float* colors    = (const float*)d_in[3];
    const int*   level_p   = (const int*)d_in[4];

    int N = in_sizes[1];                           // sizes has N elements
    float* out        = (float*)d_out;
    float* morton_out = out + (size_t)N * 8 * 32;

    int blocks = (N + P - 1) / P;
    asv_kernel<<<blocks, 256, 0, stream>>>(positions, sizes, densities, colors,
                                           level_p, out, morton_out, N);
}

// Round 4
// 57.338 us; speedup vs baseline: 3.1827x; 1.1755x over previous
//
#include <hip/hip_runtime.h>

typedef float f4 __attribute__((ext_vector_type(4)));

#define P   32   // parents per main block
#define REC 36   // dwords per LDS record: 16B-aligned stride, banks spread by 4p

__device__ __forceinline__ unsigned int part1by2(unsigned int n) {
    n &= 1023u;
    n = (n ^ (n << 16)) & 0xFF0000FFu;
    n = (n ^ (n << 8))  & 0x0300F00Fu;
    n = (n ^ (n << 4))  & 0x030C30C3u;
    n = (n ^ (n << 2))  & 0x09249249u;
    return n;
}

// Grid role-split:
//   blocks [0, mainBlocks)                 : out rows (32 f32 each), no morton
//   blocks [mainBlocks, +mortonBlocks)     : morton codes, dense 2KB/wave stores
__global__ __launch_bounds__(256) void asv_kernel(
    const float* __restrict__ positions,
    const float* __restrict__ sizes,
    const float* __restrict__ densities,
    const float* __restrict__ colors,
    const int*   __restrict__ level_p,
    float* __restrict__ out,
    float* __restrict__ morton_out,
    int N, int mainBlocks)
{
    const int tid = threadIdx.x;
    const int gr  = 64 << level_p[0];
    const float grf = (float)gr;

    if (blockIdx.x >= mainBlocks) {
        // ---------------- morton role: 1 parent per thread ----------------
        const int i = (blockIdx.x - mainBlocks) * 256 + tid;
        if (i >= N) return;
        const float s  = sizes[i];
        const float t  = 0.25f * s;                    // exact pow2 scale
        const float px = positions[3 * i + 0];
        const float py = positions[3 * i + 1];
        const float pz = positions[3 * i + 2];

        // grid cell -> interleaved bits; only 2 distinct coords per axis
        #define CELL(c) ({                                                   \
            int _v = (int)(__fmul_rn(__fmul_rn(__fadd_rn((c), 1.0f), 0.5f), grf)); \
            _v = min(max(_v, 0), gr - 1);                                    \
            part1by2((unsigned)_v); })
        const unsigned bx0 = CELL(__fadd_rn(px, -t));
        const unsigned bx1 = CELL(__fadd_rn(px,  t));
        const unsigned by0 = CELL(__fadd_rn(py, -t)) << 1;
        const unsigned by1 = CELL(__fadd_rn(py,  t)) << 1;
        const unsigned bz0 = CELL(__fadd_rn(pz, -t)) << 2;
        const unsigned bz1 = CELL(__fadd_rn(pz,  t)) << 2;
        #undef CELL

        f4 m0 = {(float)(int)(bz0 | by0 | bx0), (float)(int)(bz0 | by0 | bx1),
                 (float)(int)(bz0 | by1 | bx0), (float)(int)(bz0 | by1 | bx1)};
        f4 m1 = {(float)(int)(bz1 | by0 | bx0), (float)(int)(bz1 | by0 | bx1),
                 (float)(int)(bz1 | by1 | bx0), (float)(int)(bz1 | by1 | bx1)};
        f4* mp = (f4*)(morton_out + (size_t)i * 8);
        __builtin_nontemporal_store(m0, mp);
        __builtin_nontemporal_store(m1, mp + 1);
        return;
    }

    // ---------------- main role: out rows via LDS-staged records ----------------
    __shared__ float rec[P * REC];
    const int base = blockIdx.x * P;
    const int nloc = min(P, N - base);

    if (tid < nloc)
        rec[tid * REC + 3] = sizes[base + tid];
    if (tid >= 64 && tid < 64 + nloc)
        rec[(tid - 64) * REC + 4] = densities[base + (tid - 64)];
    if (tid >= 128 && tid < 128 + nloc * 3) {
        int k = tid - 128;
        rec[(k / 3) * REC + (k % 3)] = positions[(size_t)base * 3 + k];
    }
    for (int k = tid; k < nloc * 27; k += 256)
        rec[(k / 27) * REC + 5 + (k % 27)] = colors[(size_t)base * 27 + k];
    __syncthreads();

    const int kq = tid & 7;
    const int j  = (tid >> 3) & 7;                 // child index, loop-invariant
    const float sx = (j & 1) ? 0.25f : -0.25f;
    const float sy = (j & 2) ? 0.25f : -0.25f;
    const float sz = (j & 4) ? 0.25f : -0.25f;

    f4* __restrict__ outv = (f4*)out;
    const int qblock = blockIdx.x * (P * 64);      // first quad of this block

    #pragma unroll
    for (int u = 0; u < 8; ++u) {
        const int lq = u * 256 + tid;              // local quad 0..2047
        const int p  = lq >> 6;                    // local parent
        if (p < nloc) {
            f4 v = *(const f4*)&rec[p * REC + kq * 4];
            if (kq == 0) {
                // match jnp rounding: off*size exact, then one rounded add
                f4 w = {__fadd_rn(v.x, sx * v.w),
                        __fadd_rn(v.y, sy * v.w),
                        __fadd_rn(v.z, sz * v.w),
                        0.5f * v.w};
                v = w;
            }
            __builtin_nontemporal_store(v, &outv[qblock + lq]);
        }
    }
}

extern "C" void kernel_launch(void* const* d_in, const int* in_sizes, int n_in,
                              void* d_out, int out_size, void* d_ws, size_t ws_size,
                              hipStream_t stream) {
    const float* positions = (const float*)d_in[0];
    const float* sizes     = (const float*)d_in[1];
    const float* densities = (const float*)d_in[2];
    const float* colors    = (const float*)d_in[3];
    const int*   level_p   = (const int*)d_in[4];

    int N = in_sizes[1];                           // sizes has N elements
    float* out        = (float*)d_out;
    float* morton_out = out + (size_t)N * 8 * 32;

    int mainBlocks   = (N + P - 1) / P;
    int mortonBlocks = (N + 255) / 256;
    asv_kernel<<<mainBlocks + mortonBlocks, 256, 0, stream>>>(
        positions, sizes, densities, colors, level_p, out, morton_out,
        N, mainBlocks);
}